// Round 7
// baseline (599.120 us; speedup 1.0000x reference)
//
#include <hip/hip_runtime.h>
#include <hip/hip_bf16.h>
#include <math.h>

// Problem constants
#define HID   768
#define CHR   32
#define NSEG  2048
#define TTOK  16384
#define KF    800           // HID + CHR
#define D1    512
#define D2    512

#define W1_KT (KF / 32)     // 25 k-tiles
#define W1_NT (D1 / 32)     // 16 n-tiles
#define W2_KT (D1 / 32)     // 16
#define W2_NT (D2 / 32)     // 16
#define TR_BLOCKS (W1_KT * W1_NT + W2_KT * W2_NT)   // 400 + 256 = 656

typedef __hip_bfloat16 bf16;
typedef __attribute__((ext_vector_type(8))) short short8;   // 8 bf16 = 4 VGPR
typedef __attribute__((ext_vector_type(4))) float floatx4;

// ---------------------------------------------------------------------------
// Kernel 1: fused [pool + weight transposes].
// Blocks [0,2048): segment-mean pooling + concat -> bf16 feats; zero logits/cnt.
// Blocks [2048, 2048+656): fp32 [K][N] -> bf16 [N][K] transpose of w1 / w2.
// Branch is block-uniform; barrier only on transpose path (legal).
// ---------------------------------------------------------------------------
__global__ __launch_bounds__(256) void pool_and_transpose(
    const float* __restrict__ hs,      // [B*S, H]
    const float* __restrict__ basec,   // [N, C]
    const int*   __restrict__ tok,     // [T]
    const int*   __restrict__ seg,     // [T], sorted
    const float* __restrict__ w1,      // [KF][D1]
    const float* __restrict__ w2,      // [D1][D2]
    bf16*        __restrict__ feats,   // [N, KF] bf16
    bf16*        __restrict__ w1t,     // [D1][KF] bf16
    bf16*        __restrict__ w2t,     // [D2][D1] bf16
    float*       __restrict__ logits,  // [N] zero-init here
    int*         __restrict__ cnt)     // [N] zero-init here
{
    __shared__ float tile[32][33];
    const int tid = threadIdx.x;

    if (blockIdx.x < NSEG) {
        // ---------------- pooling path ----------------
        const int n = blockIdx.x;

        int lo;
        {
            int l = 0, r = TTOK;
            while (l < r) { int m = (l + r) >> 1; if (seg[m] < n) l = m + 1; else r = m; }
            lo = l;
        }
        int hi;
        {
            int l = lo, r = TTOK;
            while (l < r) { int m = (l + r) >> 1; if (seg[m] < n + 1) l = m + 1; else r = m; }
            hi = l;
        }

        float a0 = 0.f, a1 = 0.f, a2 = 0.f;
        int t = lo;
        for (; t + 4 <= hi; t += 4) {
            const float* r0 = hs + (long)tok[t]     * HID;
            const float* r1 = hs + (long)tok[t + 1] * HID;
            const float* r2 = hs + (long)tok[t + 2] * HID;
            const float* r3 = hs + (long)tok[t + 3] * HID;
            float x0a = r0[tid], x0b = r0[tid + 256], x0c = r0[tid + 512];
            float x1a = r1[tid], x1b = r1[tid + 256], x1c = r1[tid + 512];
            float x2a = r2[tid], x2b = r2[tid + 256], x2c = r2[tid + 512];
            float x3a = r3[tid], x3b = r3[tid + 256], x3c = r3[tid + 512];
            a0 += (x0a + x1a) + (x2a + x3a);
            a1 += (x0b + x1b) + (x2b + x3b);
            a2 += (x0c + x1c) + (x2c + x3c);
        }
        for (; t < hi; ++t) {
            const float* row = hs + (long)tok[t] * HID;
            a0 += row[tid];
            a1 += row[tid + 256];
            a2 += row[tid + 512];
        }
        const float inv = 1.0f / (float)((hi - lo) > 0 ? (hi - lo) : 1);
        bf16* frow = feats + (long)n * KF;
        frow[tid]       = __float2bfloat16(a0 * inv);
        frow[tid + 256] = __float2bfloat16(a1 * inv);
        frow[tid + 512] = __float2bfloat16(a2 * inv);
        if (tid < CHR) frow[HID + tid] = __float2bfloat16(basec[n * CHR + tid]);
        if (tid == 0) { logits[n] = 0.0f; cnt[n] = 0; }
    } else {
        // ---------------- transpose path ----------------
        int t = blockIdx.x - NSEG;
        const float* in; bf16* outp; int K, N, kt, nt;
        if (t < W1_KT * W1_NT) {
            in = w1; outp = w1t; K = KF; N = D1;
            kt = t % W1_KT; nt = t / W1_KT;
        } else {
            t -= W1_KT * W1_NT;
            in = w2; outp = w2t; K = D1; N = D2;
            kt = t & (W2_KT - 1); nt = t >> 4;
        }
        const int k0 = kt * 32;
        const int n0 = nt * 32;
        const int tx = tid & 31;
        const int ty = tid >> 5;      // 0..7

        #pragma unroll
        for (int i = 0; i < 32; i += 8)
            tile[ty + i][tx] = in[(long)(k0 + ty + i) * N + (n0 + tx)];
        __syncthreads();
        #pragma unroll
        for (int i = 0; i < 32; i += 8)
            outp[(long)(n0 + ty + i) * K + (k0 + tx)] = __float2bfloat16(tile[tx][ty + i]);
    }
}

// ---------------------------------------------------------------------------
// Kernel 2: bf16 MFMA GEMM, B^T layout: C = relu(A @ Bt^T + bias), bf16 out.
// 64x64 tile, 4 waves 2x2, wave=32x32 (2x2 16x16x32 frags), BK=32,
// reg-staged LDS with XOR chunk swizzle, T14 issue-early/write-late.
// ---------------------------------------------------------------------------
__global__ __launch_bounds__(256) void gemm_bt_relu(
    const bf16*  __restrict__ A,     // [M][K]
    const bf16*  __restrict__ Bt,    // [N][K]
    const float* __restrict__ bias,  // [N]
    bf16*        __restrict__ Cout,  // [M][N]
    int M, int N, int K)
{
    __shared__ short As[64 * 32];
    __shared__ short Bs[64 * 32];

    const int tid  = threadIdx.x;
    const int bm   = blockIdx.x * 64;
    const int bn   = blockIdx.y * 64;
    const int wave = tid >> 6;
    const int lane = tid & 63;
    const int wm   = wave >> 1;
    const int wn   = wave & 1;
    const int g    = lane >> 4;
    const int r    = lane & 15;

    const int srow = tid >> 2;
    const int sch  = tid & 3;
    const int sidx = srow * 32 + ((sch * 8) ^ ((srow & 3) << 3));

    const int nk = K / 32;

    floatx4 acc[2][2];
    #pragma unroll
    for (int i = 0; i < 2; ++i)
        #pragma unroll
        for (int j = 0; j < 2; ++j) acc[i][j] = (floatx4){0.f, 0.f, 0.f, 0.f};

    short8 areg = *(const short8*)(A  + (long)(bm + srow) * K + sch * 8);
    short8 breg = *(const short8*)(Bt + (long)(bn + srow) * K + sch * 8);
    *(short8*)(&As[sidx]) = areg;
    *(short8*)(&Bs[sidx]) = breg;

    for (int ks = 0; ks < nk; ++ks) {
        __syncthreads();

        if (ks + 1 < nk) {
            areg = *(const short8*)(A  + (long)(bm + srow) * K + (ks + 1) * 32 + sch * 8);
            breg = *(const short8*)(Bt + (long)(bn + srow) * K + (ks + 1) * 32 + sch * 8);
        }

        short8 af[2], bfr[2];
        #pragma unroll
        for (int fm = 0; fm < 2; ++fm) {
            const int ar = wm * 32 + fm * 16 + r;
            af[fm] = *(const short8*)(&As[ar * 32 + ((g * 8) ^ ((ar & 3) << 3))]);
        }
        #pragma unroll
        for (int fn = 0; fn < 2; ++fn) {
            const int br = wn * 32 + fn * 16 + r;
            bfr[fn] = *(const short8*)(&Bs[br * 32 + ((g * 8) ^ ((br & 3) << 3))]);
        }
        #pragma unroll
        for (int fm = 0; fm < 2; ++fm)
            #pragma unroll
            for (int fn = 0; fn < 2; ++fn)
                acc[fm][fn] = __builtin_amdgcn_mfma_f32_16x16x32_bf16(
                    af[fm], bfr[fn], acc[fm][fn], 0, 0, 0);

        __syncthreads();

        if (ks + 1 < nk) {
            *(short8*)(&As[sidx]) = areg;
            *(short8*)(&Bs[sidx]) = breg;
        }
    }

    #pragma unroll
    for (int fm = 0; fm < 2; ++fm) {
        #pragma unroll
        for (int fn = 0; fn < 2; ++fn) {
            const int col = bn + wn * 32 + fn * 16 + r;
            const float bv = bias[col];
            #pragma unroll
            for (int j = 0; j < 4; ++j) {
                const int row = bm + wm * 32 + fm * 16 + g * 4 + j;
                float v = fmaxf(acc[fm][fn][j] + bv, 0.0f);
                Cout[(long)row * N + col] = __float2bfloat16(v);
            }
        }
    }
}

// ---------------------------------------------------------------------------
// Kernel 3: GEMM2 + final dot + sigmoid. Per-block partial of
// relu(A@Bt^T + bias) . w3 atomicAdd'ed into logits[row]; the 8th (last)
// contributor per row (tracked via cnt[row]) reads the complete sum and
// writes sigmoid to out. Release: __threadfence between logits-add and
// cnt-add; acquire side: last block's atomic read of logits after cnt hits 7.
// ---------------------------------------------------------------------------
__global__ __launch_bounds__(256) void gemm_bt_dot_sig(
    const bf16*  __restrict__ A,      // [M][K]
    const bf16*  __restrict__ Bt,     // [N][K]
    const float* __restrict__ bias,   // [N]
    const float* __restrict__ w3,     // [N]
    const float* __restrict__ b3,     // [1]
    float*       __restrict__ logits, // [M], pre-zeroed
    int*         __restrict__ cnt,    // [M], pre-zeroed
    float*       __restrict__ out,    // [M]
    int M, int N, int K)
{
    __shared__ short As[64 * 32];
    __shared__ short Bs[64 * 32];

    const int tid  = threadIdx.x;
    const int bm   = blockIdx.x * 64;
    const int bn   = blockIdx.y * 64;
    const int wave = tid >> 6;
    const int lane = tid & 63;
    const int wm   = wave >> 1;
    const int wn   = wave & 1;
    const int g    = lane >> 4;
    const int r    = lane & 15;

    const int srow = tid >> 2;
    const int sch  = tid & 3;
    const int sidx = srow * 32 + ((sch * 8) ^ ((srow & 3) << 3));

    const int nk = K / 32;

    floatx4 acc[2][2];
    #pragma unroll
    for (int i = 0; i < 2; ++i)
        #pragma unroll
        for (int j = 0; j < 2; ++j) acc[i][j] = (floatx4){0.f, 0.f, 0.f, 0.f};

    short8 areg = *(const short8*)(A  + (long)(bm + srow) * K + sch * 8);
    short8 breg = *(const short8*)(Bt + (long)(bn + srow) * K + sch * 8);
    *(short8*)(&As[sidx]) = areg;
    *(short8*)(&Bs[sidx]) = breg;

    for (int ks = 0; ks < nk; ++ks) {
        __syncthreads();

        if (ks + 1 < nk) {
            areg = *(const short8*)(A  + (long)(bm + srow) * K + (ks + 1) * 32 + sch * 8);
            breg = *(const short8*)(Bt + (long)(bn + srow) * K + (ks + 1) * 32 + sch * 8);
        }

        short8 af[2], bfr[2];
        #pragma unroll
        for (int fm = 0; fm < 2; ++fm) {
            const int ar = wm * 32 + fm * 16 + r;
            af[fm] = *(const short8*)(&As[ar * 32 + ((g * 8) ^ ((ar & 3) << 3))]);
        }
        #pragma unroll
        for (int fn = 0; fn < 2; ++fn) {
            const int br = wn * 32 + fn * 16 + r;
            bfr[fn] = *(const short8*)(&Bs[br * 32 + ((g * 8) ^ ((br & 3) << 3))]);
        }
        #pragma unroll
        for (int fm = 0; fm < 2; ++fm)
            #pragma unroll
            for (int fn = 0; fn < 2; ++fn)
                acc[fm][fn] = __builtin_amdgcn_mfma_f32_16x16x32_bf16(
                    af[fm], bfr[fn], acc[fm][fn], 0, 0, 0);

        __syncthreads();

        if (ks + 1 < nk) {
            *(short8*)(&As[sidx]) = areg;
            *(short8*)(&Bs[sidx]) = breg;
        }
    }

    const int last = (int)gridDim.y - 1;   // contributions per row - 1
    #pragma unroll
    for (int fm = 0; fm < 2; ++fm) {
        #pragma unroll
        for (int j = 0; j < 4; ++j) {
            float s = 0.f;
            #pragma unroll
            for (int fn = 0; fn < 2; ++fn) {
                const int col = bn + wn * 32 + fn * 16 + r;
                float v = fmaxf(acc[fm][fn][j] + bias[col], 0.0f);
                s = fmaf(v, w3[col], s);
            }
            s += __shfl_xor(s, 1, 64);
            s += __shfl_xor(s, 2, 64);
            s += __shfl_xor(s, 4, 64);
            s += __shfl_xor(s, 8, 64);
            if (r == 0) {
                const int row = bm + wm * 32 + fm * 16 + g * 4 + j;
                atomicAdd(&logits[row], s);
                __threadfence();                       // release our add
                int c = atomicAdd(&cnt[row], 1);
                if (c == last) {                       // all adds visible
                    float tot = atomicAdd(&logits[row], 0.0f);  // atomic read
                    out[row] = 1.0f / (1.0f + expf(-(tot + b3[0])));
                }
            }
        }
    }
}

// ---------------------------------------------------------------------------
extern "C" void kernel_launch(void* const* d_in, const int* in_sizes, int n_in,
                              void* d_out, int out_size, void* d_ws, size_t ws_size,
                              hipStream_t stream) {
    const float* hs    = (const float*)d_in[0];
    const float* basec = (const float*)d_in[1];
    const float* w1    = (const float*)d_in[2];
    const float* b1    = (const float*)d_in[3];
    const float* w2    = (const float*)d_in[4];
    const float* b2    = (const float*)d_in[5];
    const float* w3    = (const float*)d_in[6];
    const float* b3    = (const float*)d_in[7];
    const int*   tok   = (const int*)d_in[8];
    const int*   seg   = (const int*)d_in[9];
    float*       out   = (float*)d_out;

    char* ws = (char*)d_ws;
    bf16*  feats  = (bf16*)ws;   ws += (size_t)NSEG * KF * 2;
    bf16*  w1t    = (bf16*)ws;   ws += (size_t)D1 * KF * 2;
    bf16*  w2t    = (bf16*)ws;   ws += (size_t)D2 * D1 * 2;
    bf16*  h1     = (bf16*)ws;   ws += (size_t)NSEG * D1 * 2;
    float* logits = (float*)ws;  ws += (size_t)NSEG * sizeof(float);
    int*   cnt    = (int*)ws;

    pool_and_transpose<<<NSEG + TR_BLOCKS, 256, 0, stream>>>(
        hs, basec, tok, seg, w1, w2, feats, w1t, w2t, logits, cnt);

    gemm_bt_relu<<<dim3(NSEG / 64, D1 / 64), 256, 0, stream>>>(
        feats, w1t, b1, h1, NSEG, D1, KF);

    gemm_bt_dot_sig<<<dim3(NSEG / 64, D2 / 64), 256, 0, stream>>>(
        h1, w2t, b2, w3, b3, logits, cnt, out, NSEG, D2, D1);
}